// Round 5
// baseline (177.061 us; speedup 1.0000x reference)
//
#include <hip/hip_runtime.h>

// out[p][f] = sum_s x[p][s] * K[s][f];  P = 393,216, K 64x64 fp32.
//
// R9: ledger -- R5 (copy-identical loads, scattered stores), R6 (no-LDS),
// R8b (fragmented loads, copy-identical nt stores) ALL land at 59.5us.
// Occupancy 23% => ~7.4 waves/CU avg => ~11,000 cy/tile/wave while compute
// is ~700 cy: saturated-queue equilibrium (in-flight 7.6MB / 1.68 TB/s read
// = 4.5us latency). Binding constraint is achieved stream throughput, and
// every config so far had ONE dirty stream and only 4KB/wave in flight.
// R9 = both streams copy-identical + deep pipeline + persistent grid:
//   * 512 blocks (2/CU), 4 waves, 12 tiles/wave, exact fit, no guards.
//   * loads: 4x dwordx4/tile, 1KB fully-covered contiguous per instr
//     (m13-copy-identical) -> regs; 2-tile-deep reg pipeline (8KB/wave in
//     flight, load->use = 2 iterations, vmcnt counted, never drained).
//   * regs -> wave-private LDS (double buffer), frag-read b128, MFMA.
//   * acc -> LDS transpose (reuses the JUST-CONSUMED buffer) -> 4x nt
//     dwordx4, 1KB contiguous per instr (R8b epilogue, WRITE=98MB clean).
//   * no barrier in the loop (K-build barrier only, once).
// Numerics unchanged (3-term bf16 hi/lo, absmax 0.03125).
// Prediction: dur 59.5 -> 33-42us if stream-cleanliness/windowing theory
// holds (hbm 2.5 -> 3.6-4.5 TB/s, VALUBusy ~20%); if null 57-62us, the
// structure space is exhausted -> mixed dependent R/W ceiling, ROOFLINE.

#define THREADS 256
#define WPB     4          // waves per block
#define NT      12         // tiles per wave; 512 blocks * 4 * 12 = 24576 exact
#define XS      68         // LDS row stride (floats): pad -> 2-way max on frags

typedef __attribute__((ext_vector_type(8))) short bf16x8;
typedef __attribute__((ext_vector_type(4))) float f32x4;

static __device__ __forceinline__ unsigned short bf16_rne(float f) {
    unsigned int u = __float_as_uint(f);
    u += 0x7fffu + ((u >> 16) & 1u);
    return (unsigned short)(u >> 16);
}
static __device__ __forceinline__ float bf16f(unsigned short h) {
    return __uint_as_float((unsigned int)h << 16);
}

__global__ __launch_bounds__(THREADS)
void dct_kernel(const float* __restrict__ x,
                const float* __restrict__ Kmat,
                float* __restrict__ out) {
    __shared__ short bhi[8 * 64 * 8];                    //  8 KB [combo][lane][j]
    __shared__ short blo[8 * 64 * 8];                    //  8 KB
    __shared__ __align__(16) float xb[WPB][2][16 * XS];  // 34,816 B dbuf+scratch

    const int tid  = threadIdx.x;
    const int lane = tid & 63;
    const int wv   = tid >> 6;          // 0..3
    const int l15  = lane & 15;
    const int quad = lane >> 4;         // 0..3

    const int totw = (int)gridDim.x * WPB;              // 2048 waves
    const long long wt0 = (long long)blockIdx.x * WPB + wv;
    const f32x4* src = (const f32x4*)x + wt0 * 256;     // tile base, float4 units
    const long long TS4   = (long long)totw * 256;      // float4 step per s
    float* dst = out + wt0 * 1024;
    const long long SSTEP = (long long)totw * 1024;     // float step per s

    // ---- prologue: issue tiles 0,1 (copy-identical: 1KB/instr, lane*16B) --
    f32x4 cc[2][4];                                     // tile parity t&1 -> bank
#pragma unroll
    for (int b = 0; b < 2; ++b)
#pragma unroll
        for (int i = 0; i < 4; ++i)
            cc[b][i] = src[(long long)b * TS4 + i * 64 + lane];

    // ---- build K bf16 hi/lo B-frags once; wave wv builds combos 2wv,2wv+1 --
#pragma unroll
    for (int ccx = 0; ccx < 2; ++ccx) {
        const int combo = wv * 2 + ccx;
        const int kc = combo >> 2, ft = combo & 3;
        short hh[8], ll[8];
#pragma unroll
        for (int j = 0; j < 8; ++j) {
            float v = Kmat[(kc * 32 + quad * 8 + j) * 64 + ft * 16 + l15];
            unsigned short h = bf16_rne(v);
            hh[j] = (short)h;
            ll[j] = (short)bf16_rne(v - bf16f(h));
        }
        *(bf16x8*)&bhi[(combo * 64 + lane) * 8] = *(bf16x8*)hh;
        *(bf16x8*)&blo[(combo * 64 + lane) * 8] = *(bf16x8*)ll;
    }
    __syncthreads();

    bf16x8 Bh[8], Bl[8];
#pragma unroll
    for (int c = 0; c < 8; ++c) {
        Bh[c] = *(const bf16x8*)&bhi[(c * 64 + lane) * 8];
        Bl[c] = *(const bf16x8*)&blo[(c * 64 + lane) * 8];
    }

    // ---- stage tile 0 into buf0; refill bank0 with tile 2 ----
    // reg i holds tile bytes [i*1024 + lane*16): row = i*4+quad, col = l15*4
#pragma unroll
    for (int i = 0; i < 4; ++i)
        *(f32x4*)&xb[wv][0][(i * 4 + quad) * XS + l15 * 4] = cc[0][i];
#pragma unroll
    for (int i = 0; i < 4; ++i)
        cc[0][i] = src[2 * TS4 + i * 64 + lane];

    // ---- steady loop: fully unrolled, all indices compile-time ----
#pragma unroll
    for (int s = 0; s < NT; ++s) {
        const int cur = s & 1, nxt = (s + 1) & 1;

        // frag-read tile s + convert to bf16 hi/lo
        bf16x8 Ahi[2], Alo[2];
#pragma unroll
        for (int kc = 0; kc < 2; ++kc) {
            const float* ap = &xb[wv][cur][l15 * XS + kc * 32 + quad * 8];
            float av[8];
            *(f32x4*)&av[0] = *(const f32x4*)ap;
            *(f32x4*)&av[4] = *(const f32x4*)(ap + 4);
            short ah[8], al[8];
#pragma unroll
            for (int j = 0; j < 8; ++j) {
                unsigned short h = bf16_rne(av[j]);
                ah[j] = (short)h;
                al[j] = (short)bf16_rne(av[j] - bf16f(h));
            }
            Ahi[kc] = *(bf16x8*)ah;
            Alo[kc] = *(bf16x8*)al;
        }

        f32x4 acc[4];
#pragma unroll
        for (int t = 0; t < 4; ++t) acc[t] = (f32x4){0.f, 0.f, 0.f, 0.f};
#pragma unroll
        for (int kc = 0; kc < 2; ++kc)
#pragma unroll
            for (int ft = 0; ft < 4; ++ft) {
                const int c = kc * 4 + ft;
                acc[ft] = __builtin_amdgcn_mfma_f32_16x16x32_bf16(Ahi[kc], Bh[c], acc[ft], 0, 0, 0);
                acc[ft] = __builtin_amdgcn_mfma_f32_16x16x32_bf16(Alo[kc], Bh[c], acc[ft], 0, 0, 0);
                acc[ft] = __builtin_amdgcn_mfma_f32_16x16x32_bf16(Ahi[kc], Bl[c], acc[ft], 0, 0, 0);
            }

        // stage tile s+1 (its loads were issued 2 iterations ago -> counted
        // vmcnt, ~2 full iterations of latency slack), refill bank with s+3
        if (s + 1 < NT) {
#pragma unroll
            for (int i = 0; i < 4; ++i)
                *(f32x4*)&xb[wv][nxt][(i * 4 + quad) * XS + l15 * 4] = cc[nxt][i];
        }
        if (s + 3 < NT) {
#pragma unroll
            for (int i = 0; i < 4; ++i)
                cc[nxt][i] = src[(long long)(s + 3) * TS4 + i * 64 + lane];
        }

        // transpose acc into the just-consumed buffer (same-wave DS is
        // in-order: frag-reads above precede these writes), then coalesced
        // nt stores: 1KB fully-covered contiguous per instr
#pragma unroll
        for (int ft = 0; ft < 4; ++ft)
#pragma unroll
            for (int r = 0; r < 4; ++r)
                xb[wv][cur][(quad * 4 + r) * XS + ft * 16 + l15] = acc[ft][r];
        float* ob = dst + (long long)s * SSTEP;
#pragma unroll
        for (int i = 0; i < 4; ++i) {
            f32x4 v = *(const f32x4*)&xb[wv][cur][(i * 4 + quad) * XS + l15 * 4];
            __builtin_nontemporal_store(v, (f32x4*)(ob + i * 256 + lane * 4));
        }
    }
}

extern "C" void kernel_launch(void* const* d_in, const int* in_sizes, int n_in,
                              void* d_out, int out_size, void* d_ws, size_t ws_size,
                              hipStream_t stream) {
    const float* x = (const float*)d_in[0];   // (8,3,1024,1024) fp32
    const float* K = (const float*)d_in[1];   // (64,64) fp32
    float* out = (float*)d_out;

    const int total = in_sizes[0];            // 25,165,824 floats
    const int num_patches = total / 64;       // 393,216
    const int wave_tiles  = num_patches / 16; // 24,576
    const int blocks = wave_tiles / (WPB * NT);  // 512, exact

    dct_kernel<<<blocks, THREADS, 0, stream>>>(x, K, out);
}